// Round 2
// baseline (160.811 us; speedup 1.0000x reference)
//
#include <hip/hip_runtime.h>
#include <hip/hip_bf16.h>

#define B_ 8
#define R_ 256
#define C_ 256
#define E_ 512
#define H_ 8
#define D_ 64

// ---------------------------------------------------------------------------
// GEMM: (2048 x 512) @ (512 x 512). BM=BN=64, BK=32, 4x4 register tile.
// multi=1: blockIdx.z selects {Q(row_emb,Wq,plain), K(col_emb,Wk,BHDC), V(col_emb,Wv,BHCD)}
// multi=0: plain row-major single GEMM (used for the final @Wo).
// ---------------------------------------------------------------------------
__global__ __launch_bounds__(256) void gemm512k(
    const float* __restrict__ inQ, const float* __restrict__ inKV,
    const float* __restrict__ Wa, const float* __restrict__ Wb,
    const float* __restrict__ Wc,
    float* __restrict__ o0, float* __restrict__ o1, float* __restrict__ o2,
    int multi)
{
    const int z = multi ? blockIdx.z : 0;
    const float* in  = (multi && z > 0) ? inKV : inQ;
    const float* W   = (z == 0) ? Wa : (z == 1) ? Wb : Wc;
    float* out       = (z == 0) ? o0 : (z == 1) ? o1 : o2;
    const int mode   = multi ? z : 0;

    __shared__ float As[32][64];  // [k][m]
    __shared__ float Bs[32][64];  // [k][n]

    const int t = threadIdx.x;
    const int row0 = blockIdx.x * 64;
    const int col0 = blockIdx.y * 64;
    const int ty = t >> 4, tx = t & 15;

    const int ar = t >> 2;        // A row 0..63
    const int ac = (t & 3) * 8;   // A k-col base
    const int br = t >> 3;        // B k-row 0..31
    const int bc = (t & 7) * 8;   // B col base

    float acc[4][4] = {};

    for (int k0 = 0; k0 < 512; k0 += 32) {
        float4 a0 = *(const float4*)&in[(size_t)(row0 + ar) * 512 + k0 + ac];
        float4 a1 = *(const float4*)&in[(size_t)(row0 + ar) * 512 + k0 + ac + 4];
        float4 b0 = *(const float4*)&W[(size_t)(k0 + br) * 512 + col0 + bc];
        float4 b1 = *(const float4*)&W[(size_t)(k0 + br) * 512 + col0 + bc + 4];
        __syncthreads();  // previous iter's compute done before LDS overwrite
        As[ac + 0][ar] = a0.x; As[ac + 1][ar] = a0.y;
        As[ac + 2][ar] = a0.z; As[ac + 3][ar] = a0.w;
        As[ac + 4][ar] = a1.x; As[ac + 5][ar] = a1.y;
        As[ac + 6][ar] = a1.z; As[ac + 7][ar] = a1.w;
        *(float4*)&Bs[br][bc]     = b0;
        *(float4*)&Bs[br][bc + 4] = b1;
        __syncthreads();
        #pragma unroll
        for (int k = 0; k < 32; ++k) {
            float4 av = *(const float4*)&As[k][ty * 4];
            float4 bv = *(const float4*)&Bs[k][tx * 4];
            float aa[4] = {av.x, av.y, av.z, av.w};
            float bb[4] = {bv.x, bv.y, bv.z, bv.w};
            #pragma unroll
            for (int i = 0; i < 4; ++i)
                #pragma unroll
                for (int j = 0; j < 4; ++j)
                    acc[i][j] += aa[i] * bb[j];
        }
    }

    #pragma unroll
    for (int i = 0; i < 4; ++i) {
        const int n = row0 + ty * 4 + i;
        #pragma unroll
        for (int j = 0; j < 4; ++j) {
            const int m = col0 + tx * 4 + j;
            const float v = acc[i][j];
            if (mode == 0) {
                out[(size_t)n * 512 + m] = v;                       // (rows, 512)
            } else {
                const int bb2 = n >> 8, cc = n & 255, h = m >> 6, d = m & 63;
                if (mode == 1)
                    out[(((size_t)bb2 * 8 + h) * 64 + d) * 256 + cc] = v;  // K: (B,H,D,C)
                else
                    out[(((size_t)bb2 * 8 + h) * 256 + cc) * 64 + d] = v;  // V: (B,H,C,D)
            }
        }
    }
}

// ---------------------------------------------------------------------------
// Fused attention: one block per (b, 4 rows). 256 threads.
// Phases: load -> QK^T -> score-MLP -> masked softmax -> PV -> store heads.
// ---------------------------------------------------------------------------
__global__ __launch_bounds__(256) void attn_fused(
    const float* __restrict__ Q,      // (B,R,512) row-major, m = h*64+d
    const float* __restrict__ K,      // (B,H,D,C)
    const float* __restrict__ V,      // (B,H,C,D)
    const float* __restrict__ cost,   // (B,R,C)
    const int* __restrict__ mask,     // (B,R,C) int32 (bool -> int per harness)
    const float* __restrict__ W1,     // (16,128)
    const float* __restrict__ W2,     // (128,8)
    const float* __restrict__ alpha,  // (8)
    float* __restrict__ OH)           // (B,R,512)
{
    __shared__ float q_s[4][512];          // pre-scaled by 1/sqrt(D)
    __shared__ float dot_s[4][8][256];     // dot -> logits -> weights (in place)
    __shared__ float cost_s[4][256];
    __shared__ int   mask_s[4][256];
    __shared__ float w1t[128][8];          // W1[2h][j] transposed -> [j][h]
    __shared__ float w2s[128][8];          // W2 row-major copy
    __shared__ float w1c[128];             // sum_h alpha[h]*W1[2h+1][j]

    const int t  = threadIdx.x;
    const int b  = blockIdx.y;
    const int r0 = blockIdx.x * 4;

    // ---- init loads ----
    {
        const float4* qg = (const float4*)&Q[((size_t)b * R_ + r0) * 512];
        float4 v0 = qg[t], v1 = qg[t + 256];
        v0.x *= 0.125f; v0.y *= 0.125f; v0.z *= 0.125f; v0.w *= 0.125f;
        v1.x *= 0.125f; v1.y *= 0.125f; v1.z *= 0.125f; v1.w *= 0.125f;
        ((float4*)q_s)[t]       = v0;
        ((float4*)q_s)[t + 256] = v1;
        const float4* cg = (const float4*)&cost[((size_t)b * R_ + r0) * 256];
        ((float4*)cost_s)[t] = cg[t];
        const int4* mg = (const int4*)&mask[((size_t)b * R_ + r0) * 256];
        ((int4*)mask_s)[t] = mg[t];
    }
    if (t < 128) {
        float s = 0.f;
        #pragma unroll
        for (int h = 0; h < 8; ++h) {
            w1t[t][h] = W1[(2 * h) * 128 + t];
            s += alpha[h] * W1[(2 * h + 1) * 128 + t];
            w2s[t][h] = W2[t * 8 + h];
        }
        w1c[t] = s;
    }
    __syncthreads();

    // ---- phase A: dot(h,c) for 4 rows ----
    {
        const int hg  = t >> 6;          // wave id 0..3
        const int cg4 = (t & 63) * 4;    // 4 consecutive c per lane
        #pragma unroll
        for (int hh = 0; hh < 2; ++hh) {
            const int h = hh * 4 + hg;
            const float* Kp = &K[(((size_t)b * 8 + h) * 64) * 256 + cg4];
            float acc[4][4] = {};
            #pragma unroll
            for (int d4 = 0; d4 < 16; ++d4) {
                float4 qv[4];
                #pragma unroll
                for (int r = 0; r < 4; ++r)
                    qv[r] = *(const float4*)&q_s[r][h * 64 + d4 * 4];
                #pragma unroll
                for (int dd = 0; dd < 4; ++dd) {
                    float4 kv = *(const float4*)&Kp[(size_t)(d4 * 4 + dd) * 256];
                    #pragma unroll
                    for (int r = 0; r < 4; ++r) {
                        const float qd = ((const float*)&qv[r])[dd];
                        acc[r][0] += qd * kv.x;
                        acc[r][1] += qd * kv.y;
                        acc[r][2] += qd * kv.z;
                        acc[r][3] += qd * kv.w;
                    }
                }
            }
            #pragma unroll
            for (int r = 0; r < 4; ++r)
                *(float4*)&dot_s[r][h][cg4] =
                    make_float4(acc[r][0], acc[r][1], acc[r][2], acc[r][3]);
        }
    }
    __syncthreads();

    // ---- phase B: score MLP; thread t owns column c=t for all 4 rows ----
    {
        float dotr[4][8], costr[4];
        #pragma unroll
        for (int r = 0; r < 4; ++r) {
            costr[r] = cost_s[r][t];
            #pragma unroll
            for (int h = 0; h < 8; ++h) dotr[r][h] = dot_s[r][h][t];
        }
        float lac[4][8] = {};
        for (int j = 0; j < 128; ++j) {
            const float4 wa = *(const float4*)&w1t[j][0];
            const float4 wb = *(const float4*)&w1t[j][4];
            const float  wc = w1c[j];
            const float4 va = *(const float4*)&w2s[j][0];
            const float4 vb = *(const float4*)&w2s[j][4];
            #pragma unroll
            for (int r = 0; r < 4; ++r) {
                float hp = wc * costr[r];
                hp += dotr[r][0] * wa.x + dotr[r][1] * wa.y +
                      dotr[r][2] * wa.z + dotr[r][3] * wa.w +
                      dotr[r][4] * wb.x + dotr[r][5] * wb.y +
                      dotr[r][6] * wb.z + dotr[r][7] * wb.w;
                hp = fmaxf(hp, 0.f);
                lac[r][0] += hp * va.x; lac[r][1] += hp * va.y;
                lac[r][2] += hp * va.z; lac[r][3] += hp * va.w;
                lac[r][4] += hp * vb.x; lac[r][5] += hp * vb.y;
                lac[r][6] += hp * vb.z; lac[r][7] += hp * vb.w;
            }
        }
        // each thread only touches its own column -> no cross-thread hazard
        #pragma unroll
        for (int r = 0; r < 4; ++r)
            #pragma unroll
            for (int h = 0; h < 8; ++h) dot_s[r][h][t] = lac[r][h];
    }
    __syncthreads();

    // ---- phase C: masked softmax over c, in place. wave w handles r=w ----
    {
        const int lane = t & 63;
        const int r    = t >> 6;
        #pragma unroll
        for (int h = 0; h < 8; ++h) {
            float4 lv = *(const float4*)&dot_s[r][h][lane * 4];
            const int4 mk = *(const int4*)&mask_s[r][lane * 4];
            const bool m0 = mk.x != 0, m1 = mk.y != 0;
            const bool m2 = mk.z != 0, m3 = mk.w != 0;
            const float v0 = m0 ? -INFINITY : lv.x;
            const float v1 = m1 ? -INFINITY : lv.y;
            const float v2 = m2 ? -INFINITY : lv.z;
            const float v3 = m3 ? -INFINITY : lv.w;
            float mx = fmaxf(fmaxf(v0, v1), fmaxf(v2, v3));
            #pragma unroll
            for (int off = 32; off >= 1; off >>= 1)
                mx = fmaxf(mx, __shfl_xor(mx, off));
            const float e0 = m0 ? 0.f : __expf(v0 - mx);
            const float e1 = m1 ? 0.f : __expf(v1 - mx);
            const float e2 = m2 ? 0.f : __expf(v2 - mx);
            const float e3 = m3 ? 0.f : __expf(v3 - mx);
            float sm = e0 + e1 + e2 + e3;
            #pragma unroll
            for (int off = 32; off >= 1; off >>= 1)
                sm += __shfl_xor(sm, off);
            const float inv = sm > 0.f ? 1.0f / sm : 0.f;  // all-masked -> 0
            *(float4*)&dot_s[r][h][lane * 4] =
                make_float4(e0 * inv, e1 * inv, e2 * inv, e3 * inv);
        }
    }
    __syncthreads();

    // ---- phase D: PV. wave handles one h per pass, lane = d ----
    {
        const int d = t & 63;
        #pragma unroll
        for (int pass = 0; pass < 2; ++pass) {
            const int h = pass * 4 + (t >> 6);
            const float* Vp = &V[(((size_t)b * 8 + h) * 256) * 64 + d];
            float acc[4] = {0.f, 0.f, 0.f, 0.f};
            for (int c4 = 0; c4 < 64; ++c4) {
                const float4 w0v = *(const float4*)&dot_s[0][h][c4 * 4];
                const float4 w1v = *(const float4*)&dot_s[1][h][c4 * 4];
                const float4 w2v = *(const float4*)&dot_s[2][h][c4 * 4];
                const float4 w3v = *(const float4*)&dot_s[3][h][c4 * 4];
                #pragma unroll
                for (int cc = 0; cc < 4; ++cc) {
                    const float vv = Vp[(size_t)(c4 * 4 + cc) * 64];
                    acc[0] += ((const float*)&w0v)[cc] * vv;
                    acc[1] += ((const float*)&w1v)[cc] * vv;
                    acc[2] += ((const float*)&w2v)[cc] * vv;
                    acc[3] += ((const float*)&w3v)[cc] * vv;
                }
            }
            #pragma unroll
            for (int r = 0; r < 4; ++r)
                OH[((size_t)b * R_ + r0 + r) * 512 + h * 64 + d] = acc[r];
        }
    }
}

// ---------------------------------------------------------------------------
extern "C" void kernel_launch(void* const* d_in, const int* in_sizes, int n_in,
                              void* d_out, int out_size, void* d_ws, size_t ws_size,
                              hipStream_t stream)
{
    const float* row_emb = (const float*)d_in[0];
    const float* col_emb = (const float*)d_in[1];
    const float* cost    = (const float*)d_in[2];
    const int*   mask    = (const int*)d_in[3];
    const float* Wq = (const float*)d_in[4];
    const float* Wk = (const float*)d_in[5];
    const float* Wv = (const float*)d_in[6];
    const float* Wo = (const float*)d_in[7];
    const float* W1 = (const float*)d_in[8];
    const float* W2 = (const float*)d_in[9];
    const float* alpha = (const float*)d_in[10];
    float* out = (float*)d_out;

    float* ws = (float*)d_ws;
    float* Qb = ws;                 // 1 Mi floats  (B,R,512)
    float* Kb = ws + 1048576;       // (B,H,D,C)
    float* Vb = ws + 2097152;       // (B,H,C,D)
    float* OH = ws + 3145728;       // (B,R,512)

    dim3 blk(256);
    gemm512k<<<dim3(32, 8, 3), blk, 0, stream>>>(row_emb, col_emb, Wq, Wk, Wv,
                                                 Qb, Kb, Vb, 1);
    attn_fused<<<dim3(64, 8), blk, 0, stream>>>(Qb, Kb, Vb, cost, mask,
                                                W1, W2, alpha, OH);
    gemm512k<<<dim3(32, 8, 1), blk, 0, stream>>>(OH, nullptr, Wo, nullptr, nullptr,
                                                 out, nullptr, nullptr, 0);
}

// Round 3
// 146.343 us; speedup vs baseline: 1.0989x; 1.0989x over previous
//
#include <hip/hip_runtime.h>
#include <hip/hip_bf16.h>

#define B_ 8
#define R_ 256
#define C_ 256
#define E_ 512
#define H_ 8
#define D_ 64

typedef __attribute__((ext_vector_type(8))) short s8v;
typedef __attribute__((ext_vector_type(4))) float f4v;

static __device__ __forceinline__ unsigned short f2b(float x) {
    __hip_bfloat16 h = __float2bfloat16(x);
    return *reinterpret_cast<unsigned short*>(&h);
}

// ---------------------------------------------------------------------------
// prep: f32 -> bf16 for embeddings; transpose+convert the four 512x512 weights
// into (N,K) bf16 so MFMA B-fragments read 16B contiguous per lane.
// grid 2048 x 256 threads: each thread does 2 embedding elems of each emb and
// 2 transposed-weight elems.
// ---------------------------------------------------------------------------
__global__ __launch_bounds__(256) void prep(
    const float* __restrict__ re, const float* __restrict__ ce,
    const float* __restrict__ Wq, const float* __restrict__ Wk,
    const float* __restrict__ Wv, const float* __restrict__ Wo,
    unsigned short* __restrict__ reb, unsigned short* __restrict__ ceb,
    unsigned short* __restrict__ wqt, unsigned short* __restrict__ wkt,
    unsigned short* __restrict__ wvt, unsigned short* __restrict__ wot)
{
    const int t = blockIdx.x * 256 + threadIdx.x;   // 0 .. 524287
    {
        float2 v = *(const float2*)&re[(size_t)t * 2];
        reb[t * 2]     = f2b(v.x);
        reb[t * 2 + 1] = f2b(v.y);
        float2 w = *(const float2*)&ce[(size_t)t * 2];
        ceb[t * 2]     = f2b(w.x);
        ceb[t * 2 + 1] = f2b(w.y);
    }
    {
        const int o = t * 2;                 // 0 .. 1048574, even
        const int which = o >> 18;           // 0..3
        const int idx = o & 262143;          // within one 512x512
        const float* W = which == 0 ? Wq : which == 1 ? Wk : which == 2 ? Wv : Wo;
        unsigned short* WT = which == 0 ? wqt : which == 1 ? wkt : which == 2 ? wvt : wot;
        const int n = idx >> 9, k = idx & 511;        // k even
        WT[idx]     = f2b(W[(size_t)k * 512 + n]);
        WT[idx + 1] = f2b(W[(size_t)(k + 1) * 512 + n]);
    }
}

// ---------------------------------------------------------------------------
// bf16 MFMA GEMM: (2048 x 512) @ (512 x 512), B supplied transposed (N,K).
// Block 256 thr = 4 waves, BM=BN=64; wave computes 32x32 via 2x2 MFMA tiles.
// No LDS: direct 16B/lane fragment loads (data is L2-resident).
// multi=1: z in {Q(plain f32), K->(B,H,D,C), V->(B,H,C,D)}; multi=0: plain.
// ---------------------------------------------------------------------------
__global__ __launch_bounds__(256) void gemm_bf16(
    const unsigned short* __restrict__ A0, const unsigned short* __restrict__ A1,
    const unsigned short* __restrict__ W0, const unsigned short* __restrict__ W1t,
    const unsigned short* __restrict__ W2t,
    float* __restrict__ o0, float* __restrict__ o1, float* __restrict__ o2,
    int multi)
{
    const int z = multi ? blockIdx.z : 0;
    const unsigned short* A = (multi && z > 0) ? A1 : A0;
    const unsigned short* W = (z == 0) ? W0 : (z == 1) ? W1t : W2t;
    float* out = (z == 0) ? o0 : (z == 1) ? o1 : o2;
    const int mode = multi ? z : 0;

    const int t = threadIdx.x;
    const int lane = t & 63;
    const int wave = t >> 6;
    const int row0 = blockIdx.x * 64 + (wave >> 1) * 32;
    const int col0 = blockIdx.y * 64 + (wave & 1) * 32;
    const int lrow = lane & 15;
    const int koff = (lane >> 4) * 8;

    const unsigned short* Ap0 = A + (size_t)(row0 + lrow) * 512 + koff;
    const unsigned short* Ap1 = Ap0 + 16 * 512;
    const unsigned short* Bp0 = W + (size_t)(col0 + lrow) * 512 + koff;
    const unsigned short* Bp1 = Bp0 + 16 * 512;

    f4v acc[2][2] = {};
    #pragma unroll 4
    for (int k0 = 0; k0 < 512; k0 += 32) {
        s8v a0 = *(const s8v*)(Ap0 + k0);
        s8v a1 = *(const s8v*)(Ap1 + k0);
        s8v b0 = *(const s8v*)(Bp0 + k0);
        s8v b1 = *(const s8v*)(Bp1 + k0);
        acc[0][0] = __builtin_amdgcn_mfma_f32_16x16x32_bf16(a0, b0, acc[0][0], 0, 0, 0);
        acc[0][1] = __builtin_amdgcn_mfma_f32_16x16x32_bf16(a0, b1, acc[0][1], 0, 0, 0);
        acc[1][0] = __builtin_amdgcn_mfma_f32_16x16x32_bf16(a1, b0, acc[1][0], 0, 0, 0);
        acc[1][1] = __builtin_amdgcn_mfma_f32_16x16x32_bf16(a1, b1, acc[1][1], 0, 0, 0);
    }

    const int rbase = (lane >> 4) * 4;
    #pragma unroll
    for (int i = 0; i < 2; ++i)
        #pragma unroll
        for (int j = 0; j < 2; ++j)
            #pragma unroll
            for (int reg = 0; reg < 4; ++reg) {
                const int n = row0 + i * 16 + rbase + reg;   // M index
                const int m = col0 + j * 16 + (lane & 15);   // N index
                const float v = acc[i][j][reg];
                if (mode == 0) {
                    out[(size_t)n * 512 + m] = v;
                } else {
                    const int bb = n >> 8, cc = n & 255, h = m >> 6, d = m & 63;
                    if (mode == 1)
                        out[(((size_t)bb * 8 + h) * 64 + d) * 256 + cc] = v;  // K (B,H,D,C)
                    else
                        out[(((size_t)bb * 8 + h) * 256 + cc) * 64 + d] = v;  // V (B,H,C,D)
                }
            }
}

// ---------------------------------------------------------------------------
// Fused attention: one block per (b, 2 rows). 256 threads (4 waves).
// LDS ~32.5KB -> 4 blocks/CU, grid 1024 blocks -> 16 waves/CU.
// ---------------------------------------------------------------------------
__global__ __launch_bounds__(256) void attn_fused(
    const float* __restrict__ Q,      // (B,R,512)
    const float* __restrict__ K,      // (B,H,D,C)
    const float* __restrict__ V,      // (B,H,C,D)
    const float* __restrict__ cost,   // (B,R,C)
    const int* __restrict__ mask,     // (B,R,C) int32
    const float* __restrict__ W1,     // (16,128)
    const float* __restrict__ W2,     // (128,8)
    const float* __restrict__ alpha,  // (8)
    unsigned short* __restrict__ OHb) // (B,R,512) bf16
{
    __shared__ float q_s[2][512];          // pre-scaled by 1/sqrt(D)
    __shared__ float dot_s[2][8][256];     // dot -> logits -> weights (in place)
    __shared__ float cost_s[2][256];
    __shared__ int   mask_s[2][256];
    __shared__ float w1t[128][8];          // W1[2h][j] -> [j][h]
    __shared__ float w2s[128][8];
    __shared__ float w1c[128];             // sum_h alpha[h]*W1[2h+1][j]

    const int t  = threadIdx.x;
    const int b  = blockIdx.y;
    const int r0 = blockIdx.x * 2;

    // ---- init loads ----
    {
        const float4* qg = (const float4*)&Q[((size_t)b * R_ + r0) * 512];
        float4 v0 = qg[t];
        v0.x *= 0.125f; v0.y *= 0.125f; v0.z *= 0.125f; v0.w *= 0.125f;
        ((float4*)q_s)[t] = v0;
    }
    if (t < 128) {
        const float4* cg = (const float4*)&cost[((size_t)b * R_ + r0) * 256];
        ((float4*)cost_s)[t] = cg[t];
        const int4* mg = (const int4*)&mask[((size_t)b * R_ + r0) * 256];
        ((int4*)mask_s)[t] = mg[t];
        float s = 0.f;
        #pragma unroll
        for (int h = 0; h < 8; ++h) {
            w1t[t][h] = W1[(2 * h) * 128 + t];
            s += alpha[h] * W1[(2 * h + 1) * 128 + t];
            w2s[t][h] = W2[t * 8 + h];
        }
        w1c[t] = s;
    }
    __syncthreads();

    // ---- phase A: dot(h,c) for 2 rows ----
    {
        const int hg  = t >> 6;          // wave 0..3
        const int cg4 = (t & 63) * 4;
        #pragma unroll
        for (int hh = 0; hh < 2; ++hh) {
            const int h = hh * 4 + hg;
            const float* Kp = &K[(((size_t)b * 8 + h) * 64) * 256 + cg4];
            float acc[2][4] = {};
            #pragma unroll
            for (int d4 = 0; d4 < 16; ++d4) {
                const float4 qv0 = *(const float4*)&q_s[0][h * 64 + d4 * 4];
                const float4 qv1 = *(const float4*)&q_s[1][h * 64 + d4 * 4];
                #pragma unroll
                for (int dd = 0; dd < 4; ++dd) {
                    const float4 kv = *(const float4*)&Kp[(size_t)(d4 * 4 + dd) * 256];
                    const float q0 = ((const float*)&qv0)[dd];
                    const float q1 = ((const float*)&qv1)[dd];
                    acc[0][0] += q0 * kv.x; acc[0][1] += q0 * kv.y;
                    acc[0][2] += q0 * kv.z; acc[0][3] += q0 * kv.w;
                    acc[1][0] += q1 * kv.x; acc[1][1] += q1 * kv.y;
                    acc[1][2] += q1 * kv.z; acc[1][3] += q1 * kv.w;
                }
            }
            *(float4*)&dot_s[0][h][cg4] = make_float4(acc[0][0], acc[0][1], acc[0][2], acc[0][3]);
            *(float4*)&dot_s[1][h][cg4] = make_float4(acc[1][0], acc[1][1], acc[1][2], acc[1][3]);
        }
    }
    __syncthreads();

    // ---- phase B: score MLP; thread t owns column c=t for both rows ----
    {
        float dotr[2][8], costr[2];
        #pragma unroll
        for (int r = 0; r < 2; ++r) {
            costr[r] = cost_s[r][t];
            #pragma unroll
            for (int h = 0; h < 8; ++h) dotr[r][h] = dot_s[r][h][t];
        }
        float lac[2][8] = {};
        for (int j = 0; j < 128; ++j) {
            const float4 wa = *(const float4*)&w1t[j][0];
            const float4 wb = *(const float4*)&w1t[j][4];
            const float  wc = w1c[j];
            const float4 va = *(const float4*)&w2s[j][0];
            const float4 vb = *(const float4*)&w2s[j][4];
            #pragma unroll
            for (int r = 0; r < 2; ++r) {
                float hp = wc * costr[r];
                hp += dotr[r][0] * wa.x + dotr[r][1] * wa.y +
                      dotr[r][2] * wa.z + dotr[r][3] * wa.w +
                      dotr[r][4] * wb.x + dotr[r][5] * wb.y +
                      dotr[r][6] * wb.z + dotr[r][7] * wb.w;
                hp = fmaxf(hp, 0.f);
                lac[r][0] += hp * va.x; lac[r][1] += hp * va.y;
                lac[r][2] += hp * va.z; lac[r][3] += hp * va.w;
                lac[r][4] += hp * vb.x; lac[r][5] += hp * vb.y;
                lac[r][6] += hp * vb.z; lac[r][7] += hp * vb.w;
            }
        }
        #pragma unroll
        for (int r = 0; r < 2; ++r)
            #pragma unroll
            for (int h = 0; h < 8; ++h) dot_s[r][h][t] = lac[r][h];
    }
    __syncthreads();

    // ---- phase C: masked softmax; wave w handles 4 (r,h) pairs ----
    {
        const int lane = t & 63;
        const int w    = t >> 6;
        #pragma unroll
        for (int p = 0; p < 4; ++p) {
            const int idx = w * 4 + p;     // 0..15
            const int r = idx >> 3;
            const int h = idx & 7;
            float4 lv = *(const float4*)&dot_s[r][h][lane * 4];
            const int4 mk = *(const int4*)&mask_s[r][lane * 4];
            const bool m0 = mk.x != 0, m1 = mk.y != 0;
            const bool m2 = mk.z != 0, m3 = mk.w != 0;
            const float v0 = m0 ? -INFINITY : lv.x;
            const float v1 = m1 ? -INFINITY : lv.y;
            const float v2 = m2 ? -INFINITY : lv.z;
            const float v3 = m3 ? -INFINITY : lv.w;
            float mx = fmaxf(fmaxf(v0, v1), fmaxf(v2, v3));
            #pragma unroll
            for (int off = 32; off >= 1; off >>= 1)
                mx = fmaxf(mx, __shfl_xor(mx, off));
            const float e0 = m0 ? 0.f : __expf(v0 - mx);
            const float e1 = m1 ? 0.f : __expf(v1 - mx);
            const float e2 = m2 ? 0.f : __expf(v2 - mx);
            const float e3 = m3 ? 0.f : __expf(v3 - mx);
            float sm = e0 + e1 + e2 + e3;
            #pragma unroll
            for (int off = 32; off >= 1; off >>= 1)
                sm += __shfl_xor(sm, off);
            const float inv = sm > 0.f ? 1.0f / sm : 0.f;  // all-masked -> 0
            *(float4*)&dot_s[r][h][lane * 4] =
                make_float4(e0 * inv, e1 * inv, e2 * inv, e3 * inv);
        }
    }
    __syncthreads();

    // ---- phase D: PV; wave handles one h per pass, lane = d ----
    {
        const int d = t & 63;
        #pragma unroll
        for (int pass = 0; pass < 2; ++pass) {
            const int h = pass * 4 + (t >> 6);
            const float* Vp = &V[(((size_t)b * 8 + h) * 256) * 64 + d];
            float acc[2] = {0.f, 0.f};
            for (int c4 = 0; c4 < 64; ++c4) {
                const float4 w0v = *(const float4*)&dot_s[0][h][c4 * 4];
                const float4 w1v = *(const float4*)&dot_s[1][h][c4 * 4];
                #pragma unroll
                for (int cc = 0; cc < 4; ++cc) {
                    const float vv = Vp[(size_t)(c4 * 4 + cc) * 64];
                    acc[0] += ((const float*)&w0v)[cc] * vv;
                    acc[1] += ((const float*)&w1v)[cc] * vv;
                }
            }
            #pragma unroll
            for (int r = 0; r < 2; ++r)
                OHb[((size_t)b * R_ + r0 + r) * 512 + h * 64 + d] = f2b(acc[r]);
        }
    }
}

// ---------------------------------------------------------------------------
extern "C" void kernel_launch(void* const* d_in, const int* in_sizes, int n_in,
                              void* d_out, int out_size, void* d_ws, size_t ws_size,
                              hipStream_t stream)
{
    const float* row_emb = (const float*)d_in[0];
    const float* col_emb = (const float*)d_in[1];
    const float* cost    = (const float*)d_in[2];
    const int*   mask    = (const int*)d_in[3];
    const float* Wq = (const float*)d_in[4];
    const float* Wk = (const float*)d_in[5];
    const float* Wv = (const float*)d_in[6];
    const float* Wo = (const float*)d_in[7];
    const float* W1 = (const float*)d_in[8];
    const float* W2 = (const float*)d_in[9];
    const float* alpha = (const float*)d_in[10];
    float* out = (float*)d_out;

    float* ws = (float*)d_ws;
    float* Qb = ws;                                        // 1M f32
    float* Kb = ws + 1048576;                              // 1M f32 (B,H,D,C)
    float* Vb = ws + 2097152;                              // 1M f32 (B,H,C,D)
    unsigned short* OHb = (unsigned short*)(ws + 3145728); // 1M bf16
    unsigned short* reb = (unsigned short*)(ws + 3670016); // 1M bf16
    unsigned short* ceb = (unsigned short*)(ws + 4194304); // 1M bf16
    unsigned short* wqt = (unsigned short*)(ws + 4718592); // 256K bf16
    unsigned short* wkt = (unsigned short*)(ws + 4849664);
    unsigned short* wvt = (unsigned short*)(ws + 4980736);
    unsigned short* wot = (unsigned short*)(ws + 5111808); // end: 5242880 f32 = 20MB

    dim3 blk(256);
    prep<<<2048, blk, 0, stream>>>(row_emb, col_emb, Wq, Wk, Wv, Wo,
                                   reb, ceb, wqt, wkt, wvt, wot);
    gemm_bf16<<<dim3(32, 8, 3), blk, 0, stream>>>(reb, ceb, wqt, wkt, wvt,
                                                  Qb, Kb, Vb, 1);
    attn_fused<<<dim3(128, 8), blk, 0, stream>>>(Qb, Kb, Vb, cost, mask,
                                                 W1, W2, alpha, OHb);
    gemm_bf16<<<dim3(32, 8, 1), blk, 0, stream>>>(OHb, nullptr, wot, nullptr, nullptr,
                                                  out, nullptr, nullptr, 0);
}

// Round 5
// 116.819 us; speedup vs baseline: 1.3766x; 1.2527x over previous
//
#include <hip/hip_runtime.h>
#include <hip/hip_bf16.h>

#define B_ 8
#define R_ 256
#define C_ 256
#define H_ 8
#define D_ 64

typedef __attribute__((ext_vector_type(8))) short s8v;
typedef __attribute__((ext_vector_type(4))) float f4v;

static __device__ __forceinline__ unsigned short f2b(float x) {
    __hip_bfloat16 h = __float2bfloat16(x);
    return *reinterpret_cast<unsigned short*>(&h);
}

// ---------------------------------------------------------------------------
// prep: f32 -> bf16 embeddings; transpose+convert the four 512x512 weights to
// (N,K) bf16 for MFMA fragment loads.
// ---------------------------------------------------------------------------
__global__ __launch_bounds__(256) void prep(
    const float* __restrict__ re, const float* __restrict__ ce,
    const float* __restrict__ Wq, const float* __restrict__ Wk,
    const float* __restrict__ Wv, const float* __restrict__ Wo,
    unsigned short* __restrict__ reb, unsigned short* __restrict__ ceb,
    unsigned short* __restrict__ wqt, unsigned short* __restrict__ wkt,
    unsigned short* __restrict__ wvt, unsigned short* __restrict__ wot)
{
    const int t = blockIdx.x * 256 + threadIdx.x;   // 0 .. 524287
    {
        float2 v = *(const float2*)&re[(size_t)t * 2];
        reb[t * 2]     = f2b(v.x);
        reb[t * 2 + 1] = f2b(v.y);
        float2 w = *(const float2*)&ce[(size_t)t * 2];
        ceb[t * 2]     = f2b(w.x);
        ceb[t * 2 + 1] = f2b(w.y);
    }
    {
        const int o = t * 2;
        const int which = o >> 18;
        const int idx = o & 262143;
        const float* W = which == 0 ? Wq : which == 1 ? Wk : which == 2 ? Wv : Wo;
        unsigned short* WT = which == 0 ? wqt : which == 1 ? wkt : which == 2 ? wvt : wot;
        const int n = idx >> 9, k = idx & 511;
        WT[idx]     = f2b(W[(size_t)k * 512 + n]);
        WT[idx + 1] = f2b(W[(size_t)(k + 1) * 512 + n]);
    }
}

// ---------------------------------------------------------------------------
// QKV projection, bf16 in / bf16 out.
// z=0: Q = row_emb@Wq  -> (B,R,512) bf16
// z=1: K = col_emb@Wk  -> (B,H,C,D) bf16   (QK^T B-frag: k=d contiguous)
// z=2: V = col_emb@Wv  -> (B,H,D,C) bf16   (PV  B-frag: k=c contiguous)
//      computed with operands swapped (A=WvT, B=ceb) so C/D lands transposed.
// ---------------------------------------------------------------------------
__global__ __launch_bounds__(256) void gemm_qkv(
    const unsigned short* __restrict__ reb, const unsigned short* __restrict__ ceb,
    const unsigned short* __restrict__ wqt, const unsigned short* __restrict__ wkt,
    const unsigned short* __restrict__ wvt,
    unsigned short* __restrict__ Qb, unsigned short* __restrict__ Kb,
    unsigned short* __restrict__ VT)
{
    const int z = blockIdx.z;
    const unsigned short* A;
    const unsigned short* Bm;
    int Ar0, Br0;
    if (z == 0)      { A = reb; Bm = wqt; Ar0 = blockIdx.x * 64; Br0 = blockIdx.y * 64; }
    else if (z == 1) { A = ceb; Bm = wkt; Ar0 = blockIdx.x * 64; Br0 = blockIdx.y * 64; }
    else             { A = wvt; Bm = ceb; Ar0 = blockIdx.y * 64; Br0 = blockIdx.x * 64; }

    const int t = threadIdx.x, lane = t & 63, wave = t >> 6;
    const int row0 = Ar0 + (wave >> 1) * 32;
    const int col0 = Br0 + (wave & 1) * 32;
    const int lr = lane & 15, ko = (lane >> 4) * 8;

    const unsigned short* Ap0 = A + (size_t)(row0 + lr) * 512 + ko;
    const unsigned short* Ap1 = Ap0 + 16 * 512;
    const unsigned short* Bp0 = Bm + (size_t)(col0 + lr) * 512 + ko;
    const unsigned short* Bp1 = Bp0 + 16 * 512;

    f4v acc[2][2] = {};
    #pragma unroll 4
    for (int k0 = 0; k0 < 512; k0 += 32) {
        s8v a0 = *(const s8v*)(Ap0 + k0);
        s8v a1 = *(const s8v*)(Ap1 + k0);
        s8v b0 = *(const s8v*)(Bp0 + k0);
        s8v b1 = *(const s8v*)(Bp1 + k0);
        acc[0][0] = __builtin_amdgcn_mfma_f32_16x16x32_bf16(a0, b0, acc[0][0], 0, 0, 0);
        acc[0][1] = __builtin_amdgcn_mfma_f32_16x16x32_bf16(a0, b1, acc[0][1], 0, 0, 0);
        acc[1][0] = __builtin_amdgcn_mfma_f32_16x16x32_bf16(a1, b0, acc[1][0], 0, 0, 0);
        acc[1][1] = __builtin_amdgcn_mfma_f32_16x16x32_bf16(a1, b1, acc[1][1], 0, 0, 0);
    }

    const int rbase = (lane >> 4) * 4;
    #pragma unroll
    for (int i = 0; i < 2; ++i)
        #pragma unroll
        for (int j = 0; j < 2; ++j)
            #pragma unroll
            for (int reg = 0; reg < 4; ++reg) {
                const int rowIdx = row0 + i * 16 + rbase + reg;  // A's M index
                const int colIdx = col0 + j * 16 + lr;           // B's N index
                const unsigned short v = f2b(acc[i][j][reg]);
                if (z == 0) {
                    Qb[(size_t)rowIdx * 512 + colIdx] = v;
                } else if (z == 1) {
                    const int b = rowIdx >> 8, c = rowIdx & 255;
                    const int h = colIdx >> 6, d = colIdx & 63;
                    Kb[(((size_t)b * 8 + h) * 256 + c) * 64 + d] = v;
                } else {
                    const int h = rowIdx >> 6, d = rowIdx & 63;
                    const int b = colIdx >> 8, c = colIdx & 255;
                    VT[(((size_t)b * 8 + h) * 64 + d) * 256 + c] = v;
                }
            }
}

// ---------------------------------------------------------------------------
// Final projection: out = OH(bf16) @ WoT(bf16) -> f32 (2048 x 512).
// ---------------------------------------------------------------------------
__global__ __launch_bounds__(256) void gemm_out(
    const unsigned short* __restrict__ OHb, const unsigned short* __restrict__ wot,
    float* __restrict__ out)
{
    const int t = threadIdx.x, lane = t & 63, wave = t >> 6;
    const int row0 = blockIdx.x * 64 + (wave >> 1) * 32;
    const int col0 = blockIdx.y * 64 + (wave & 1) * 32;
    const int lr = lane & 15, ko = (lane >> 4) * 8;

    const unsigned short* Ap0 = OHb + (size_t)(row0 + lr) * 512 + ko;
    const unsigned short* Ap1 = Ap0 + 16 * 512;
    const unsigned short* Bp0 = wot + (size_t)(col0 + lr) * 512 + ko;
    const unsigned short* Bp1 = Bp0 + 16 * 512;

    f4v acc[2][2] = {};
    #pragma unroll 4
    for (int k0 = 0; k0 < 512; k0 += 32) {
        s8v a0 = *(const s8v*)(Ap0 + k0);
        s8v a1 = *(const s8v*)(Ap1 + k0);
        s8v b0 = *(const s8v*)(Bp0 + k0);
        s8v b1 = *(const s8v*)(Bp1 + k0);
        acc[0][0] = __builtin_amdgcn_mfma_f32_16x16x32_bf16(a0, b0, acc[0][0], 0, 0, 0);
        acc[0][1] = __builtin_amdgcn_mfma_f32_16x16x32_bf16(a0, b1, acc[0][1], 0, 0, 0);
        acc[1][0] = __builtin_amdgcn_mfma_f32_16x16x32_bf16(a1, b0, acc[1][0], 0, 0, 0);
        acc[1][1] = __builtin_amdgcn_mfma_f32_16x16x32_bf16(a1, b1, acc[1][1], 0, 0, 0);
    }

    const int rbase = (lane >> 4) * 4;
    #pragma unroll
    for (int i = 0; i < 2; ++i)
        #pragma unroll
        for (int j = 0; j < 2; ++j)
            #pragma unroll
            for (int reg = 0; reg < 4; ++reg)
                out[(size_t)(row0 + i * 16 + rbase + reg) * 512 + col0 + j * 16 + lr] =
                    acc[i][j][reg];
}

// ---------------------------------------------------------------------------
// Fused attention: one block per (b, 4 rows). 256 threads (4 waves).
// A: QK^T via MFMA (4 of 16 M-rows used) -> dot_s f32
// B: score MLP f32 VALU (thread t owns column c=t, 4 rows)
// C: masked softmax -> w_s bf16
// D: PV via MFMA -> OHb bf16
// ---------------------------------------------------------------------------
__global__ __launch_bounds__(256) void attn_fused(
    const unsigned short* __restrict__ Qb,  // (B,R,512) bf16
    const unsigned short* __restrict__ Kb,  // (B,H,C,D) bf16
    const unsigned short* __restrict__ VT,  // (B,H,D,C) bf16
    const float* __restrict__ cost,         // (B,R,C)
    const int* __restrict__ mask,           // (B,R,C) int32
    const float* __restrict__ W1,           // (16,128)
    const float* __restrict__ W2,           // (128,8)
    const float* __restrict__ alpha,        // (8)
    unsigned short* __restrict__ OHb)       // (B,R,512) bf16
{
    __shared__ unsigned short q_s[4][512];     // 4 KB bf16
    __shared__ float dot_s[4][8][256];         // 32 KB (dot -> logits in place)
    __shared__ unsigned short w_s[4][8][256];  // 16 KB bf16 softmax weights
    __shared__ float cost_s[4][256];           // 4 KB
    __shared__ int   mask_s[4][256];           // 4 KB
    __shared__ float w1t[128][8];
    __shared__ float w2s[128][8];
    __shared__ float w1c[128];

    const int t    = threadIdx.x;
    const int lane = t & 63;
    const int w    = t >> 6;
    const int b    = blockIdx.y;
    const int r0   = blockIdx.x * 4;

    // ---- init loads ----
    ((s8v*)q_s)[t]        = ((const s8v*)&Qb[((size_t)b * R_ + r0) * 512])[t];
    ((float4*)cost_s)[t]  = ((const float4*)&cost[((size_t)b * R_ + r0) * 256])[t];
    ((int4*)mask_s)[t]    = ((const int4*)&mask[((size_t)b * R_ + r0) * 256])[t];
    if (t < 128) {
        float s = 0.f;
        #pragma unroll
        for (int h = 0; h < 8; ++h) {
            w1t[t][h] = W1[(2 * h) * 128 + t];
            s += alpha[h] * W1[(2 * h + 1) * 128 + t];
            w2s[t][h] = W2[t * 8 + h];
        }
        w1c[t] = s;
    }
    __syncthreads();

    // ---- phase A: QK^T via MFMA; wave w handles h = {w, w+4} ----
    {
        const int rr = lane & 3;            // A row (wrapped onto 4 real rows)
        const int ko = (lane >> 4) * 8;
        #pragma unroll
        for (int hh = 0; hh < 2; ++hh) {
            const int h = hh * 4 + w;
            const s8v a0 = *(const s8v*)&q_s[rr][h * 64 + ko];
            const s8v a1 = *(const s8v*)&q_s[rr][h * 64 + 32 + ko];
            const unsigned short* Kp = Kb + (((size_t)b * 8 + h) * 256) * 64;
            #pragma unroll
            for (int ct = 0; ct < 16; ++ct) {
                const unsigned short* Bp = Kp + (size_t)(ct * 16 + (lane & 15)) * 64 + ko;
                const s8v b0 = *(const s8v*)Bp;
                const s8v b1 = *(const s8v*)(Bp + 32);
                f4v acc = {};
                acc = __builtin_amdgcn_mfma_f32_16x16x32_bf16(a0, b0, acc, 0, 0, 0);
                acc = __builtin_amdgcn_mfma_f32_16x16x32_bf16(a1, b1, acc, 0, 0, 0);
                if (lane < 16) {
                    #pragma unroll
                    for (int reg = 0; reg < 4; ++reg)
                        dot_s[reg][h][ct * 16 + lane] = acc[reg] * 0.125f;
                }
            }
        }
    }
    __syncthreads();

    // ---- phase B: score MLP (f32); thread t owns column c=t, 4 rows ----
    {
        float dotr[4][8], costr[4];
        #pragma unroll
        for (int r = 0; r < 4; ++r) {
            costr[r] = cost_s[r][t];
            #pragma unroll
            for (int h = 0; h < 8; ++h) dotr[r][h] = dot_s[r][h][t];
        }
        float lac[4][8] = {};
        for (int j = 0; j < 128; ++j) {
            const float4 wa = *(const float4*)&w1t[j][0];
            const float4 wb = *(const float4*)&w1t[j][4];
            const float  wc = w1c[j];
            const float4 va = *(const float4*)&w2s[j][0];
            const float4 vb = *(const float4*)&w2s[j][4];
            #pragma unroll
            for (int r = 0; r < 4; ++r) {
                float hp = wc * costr[r];
                hp += dotr[r][0] * wa.x + dotr[r][1] * wa.y +
                      dotr[r][2] * wa.z + dotr[r][3] * wa.w +
                      dotr[r][4] * wb.x + dotr[r][5] * wb.y +
                      dotr[r][6] * wb.z + dotr[r][7] * wb.w;
                hp = fmaxf(hp, 0.f);
                lac[r][0] += hp * va.x; lac[r][1] += hp * va.y;
                lac[r][2] += hp * va.z; lac[r][3] += hp * va.w;
                lac[r][4] += hp * vb.x; lac[r][5] += hp * vb.y;
                lac[r][6] += hp * vb.z; lac[r][7] += hp * vb.w;
            }
        }
        #pragma unroll
        for (int r = 0; r < 4; ++r)
            #pragma unroll
            for (int h = 0; h < 8; ++h) dot_s[r][h][t] = lac[r][h];
    }
    __syncthreads();

    // ---- phase C: masked softmax; wave w owns row r=w (8 h passes) ----
    {
        const int r = w;
        #pragma unroll
        for (int h = 0; h < 8; ++h) {
            float4 lv = *(const float4*)&dot_s[r][h][lane * 4];
            const int4 mk = *(const int4*)&mask_s[r][lane * 4];
            const bool m0 = mk.x != 0, m1 = mk.y != 0;
            const bool m2 = mk.z != 0, m3 = mk.w != 0;
            const float v0 = m0 ? -INFINITY : lv.x;
            const float v1 = m1 ? -INFINITY : lv.y;
            const float v2 = m2 ? -INFINITY : lv.z;
            const float v3 = m3 ? -INFINITY : lv.w;
            float mx = fmaxf(fmaxf(v0, v1), fmaxf(v2, v3));
            #pragma unroll
            for (int off = 32; off >= 1; off >>= 1)
                mx = fmaxf(mx, __shfl_xor(mx, off));
            const float e0 = m0 ? 0.f : __expf(v0 - mx);
            const float e1 = m1 ? 0.f : __expf(v1 - mx);
            const float e2 = m2 ? 0.f : __expf(v2 - mx);
            const float e3 = m3 ? 0.f : __expf(v3 - mx);
            float sm = e0 + e1 + e2 + e3;
            #pragma unroll
            for (int off = 32; off >= 1; off >>= 1)
                sm += __shfl_xor(sm, off);
            const float inv = sm > 0.f ? 1.0f / sm : 0.f;  // all-masked -> 0
            unsigned short* wp = &w_s[r][h][lane * 4];
            wp[0] = f2b(e0 * inv);
            wp[1] = f2b(e1 * inv);
            wp[2] = f2b(e2 * inv);
            wp[3] = f2b(e3 * inv);
        }
    }
    __syncthreads();

    // ---- phase D: PV via MFMA; wave w handles h = {w, w+4} ----
    {
        const int rr = lane & 3;
        const int ko = (lane >> 4) * 8;
        #pragma unroll
        for (int hh = 0; hh < 2; ++hh) {
            const int h = hh * 4 + w;
            s8v afr[8];
            #pragma unroll
            for (int kt = 0; kt < 8; ++kt)
                afr[kt] = *(const s8v*)&w_s[rr][h][kt * 32 + ko];
            const unsigned short* Vp = VT + (((size_t)b * 8 + h) * 64) * 256;
            #pragma unroll
            for (int dt = 0; dt < 4; ++dt) {
                const unsigned short* Bp = Vp + (size_t)(dt * 16 + (lane & 15)) * 256 + ko;
                f4v acc = {};
                #pragma unroll
                for (int kt = 0; kt < 8; ++kt)
                    acc = __builtin_amdgcn_mfma_f32_16x16x32_bf16(
                        afr[kt], *(const s8v*)(Bp + kt * 32), acc, 0, 0, 0);
                if (lane < 16) {
                    #pragma unroll
                    for (int reg = 0; reg < 4; ++reg)
                        OHb[((size_t)b * R_ + r0 + reg) * 512 + h * 64 + dt * 16 + lane] =
                            f2b(acc[reg]);
                }
            }
        }
    }
}

// ---------------------------------------------------------------------------
extern "C" void kernel_launch(void* const* d_in, const int* in_sizes, int n_in,
                              void* d_out, int out_size, void* d_ws, size_t ws_size,
                              hipStream_t stream)
{
    const float* row_emb = (const float*)d_in[0];
    const float* col_emb = (const float*)d_in[1];
    const float* cost    = (const float*)d_in[2];
    const int*   mask    = (const int*)d_in[3];
    const float* Wq = (const float*)d_in[4];
    const float* Wk = (const float*)d_in[5];
    const float* Wv = (const float*)d_in[6];
    const float* Wo = (const float*)d_in[7];
    const float* W1 = (const float*)d_in[8];
    const float* W2 = (const float*)d_in[9];
    const float* alpha = (const float*)d_in[10];
    float* out = (float*)d_out;

    unsigned short* base = (unsigned short*)d_ws;
    unsigned short* Qb  = base;             // 1,048,576 shorts (B,R,512)
    unsigned short* Kb  = base + 1048576;   // (B,H,C,D)
    unsigned short* VT  = base + 2097152;   // (B,H,D,C)
    unsigned short* OHb = base + 3145728;   // (B,R,512)
    unsigned short* reb = base + 4194304;   // (B,R,512)
    unsigned short* ceb = base + 5242880;   // (B,C,512)
    unsigned short* wqt = base + 6291456;   // 262,144 shorts each (512x512)
    unsigned short* wkt = base + 6553600;
    unsigned short* wvt = base + 6815744;
    unsigned short* wot = base + 7077888;   // end 7,340,032 shorts = 14.7 MB

    dim3 blk(256);
    prep<<<2048, blk, 0, stream>>>(row_emb, col_emb, Wq, Wk, Wv, Wo,
                                   reb, ceb, wqt, wkt, wvt, wot);
    gemm_qkv<<<dim3(32, 8, 3), blk, 0, stream>>>(reb, ceb, wqt, wkt, wvt,
                                                 Qb, Kb, VT);
    attn_fused<<<dim3(64, 8), blk, 0, stream>>>(Qb, Kb, VT, cost, mask,
                                                W1, W2, alpha, OHb);
    gemm_out<<<dim3(32, 8), blk, 0, stream>>>(OHb, wot, out);
}